// Round 3
// baseline (961.576 us; speedup 1.0000x reference)
//
#include <hip/hip_runtime.h>
#include <math.h>

#define N_PTS 8192
#define D_FEAT 768

// ---------------- FPS + global/component safety: one block per batch ----------------
// FPS sequence is prefix-consistent in num_samples, so one 256-step run per
// batch serves all three scales. idx layout: g[0,512) c[512,768) d[768,896)
__global__ __launch_bounds__(1024, 4) void fps_kernel(const float* __restrict__ coords,
                                                      int* __restrict__ idx_all,
                                                      float* __restrict__ safety_all) {
#pragma clang fp contract(off)
    const int b = blockIdx.x;         // 0..1
    const int t = threadIdx.x;
    const float* cb = coords + (size_t)b * N_PTS * 3;
    int* og = idx_all + b * 256;
    int* oc = idx_all + 512 + b * 128;
    int* od = idx_all + 768 + b * 64;

    // per-thread state in registers
    float px[8], py[8], pz[8], dist[8], d2ub[8];
#pragma unroll
    for (int k = 0; k < 8; k++) {
        int p = t + k * 1024;
        px[k] = cb[p * 3 + 0];
        py[k] = cb[p * 3 + 1];
        pz[k] = cb[p * 3 + 2];
    }
    // PIN the coords in VGPRs: the asm is now the defining op, so the compiler
    // cannot rematerialize the global loads inside the i-loop (round-2 bug:
    // it sank the loads into the loop -> 107 MB L2 re-read, 2.8us/iter).
#pragma unroll
    for (int k = 0; k < 8; k++) {
        asm volatile("" : "+v"(px[k]), "+v"(py[k]), "+v"(pz[k]));
    }
#pragma unroll
    for (int k = 0; k < 8; k++) { dist[k] = INFINITY; d2ub[k] = INFINITY; }

    __shared__ float red_d[2][16];
    __shared__ int   red_i[2][16];
    __shared__ int   sel[256];
    if (t == 0) { og[0] = 0; oc[0] = 0; od[0] = 0; sel[0] = 0; }
    __syncthreads();

    const int lane = t & 63, wid = t >> 6;
    int lastIdx = 0;
    for (int i = 1; i < 256; i++) {
        // broadcast read of current center coords (uniform address, L1-hot)
        const float lx = cb[lastIdx * 3 + 0];
        const float ly = cb[lastIdx * 3 + 1];
        const float lz = cb[lastIdx * 3 + 2];
#pragma unroll
        for (int k = 0; k < 8; k++) {
            float dx = px[k] - lx, dy = py[k] - ly, dz = pz[k] - lz;
            float d2 = dx * dx + dy * dy + dz * dz;   // contract off: numpy op order
            // conservative filter: only take sqrt path if it could change dist.
            // margin (1+2e-6) > (1+ulp)^3 guarantees no false negatives.
            if (__any(d2 < d2ub[k])) {
                float d = sqrtf(d2);                  // correctly rounded = np.sqrt
                float nd = fminf(dist[k], d);
                dist[k] = nd;
                d2ub[k] = nd * nd * 1.000002f;
            }
        }
        // per-thread argmax (ascending k = ascending global idx -> first-max)
        float bd = dist[0]; int bk = 0;
#pragma unroll
        for (int k = 1; k < 8; k++) if (dist[k] > bd) { bd = dist[k]; bk = k; }
        int bi = t + bk * 1024;
        // wave argmax, first-index tie-break
#pragma unroll
        for (int off = 32; off >= 1; off >>= 1) {
            float odv = __shfl_down(bd, off, 64);
            int   oiv = __shfl_down(bi, off, 64);
            if (odv > bd || (odv == bd && oiv < bi)) { bd = odv; bi = oiv; }
        }
        if (lane == 0) { red_d[i & 1][wid] = bd; red_i[i & 1][wid] = bi; }
        __syncthreads();   // single barrier per iteration (parity double-buffer)
        float fbd = red_d[i & 1][0]; int fbi = red_i[i & 1][0];
#pragma unroll
        for (int w = 1; w < 16; w++) {
            float odv = red_d[i & 1][w]; int oiv = red_i[i & 1][w];
            if (odv > fbd || (odv == fbd && oiv < fbi)) { fbd = odv; fbi = oiv; }
        }
        lastIdx = fbi;
        // zero the picked point (no dynamic register indexing)
#pragma unroll
        for (int k = 0; k < 8; k++)
            if (fbi == t + k * 1024) { dist[k] = 0.0f; d2ub[k] = 0.0f; }
        if (t == 0) {
            sel[i] = fbi;
            og[i] = fbi;
            if (i < 128) oc[i] = fbi;
            if (i < 64)  od[i] = fbi;
        }
    }

    // ---- tail: global & component safety (z already in registers) ----
    float s1 = 0.f, s2 = 0.f;
#pragma unroll
    for (int k = 0; k < 8; k++) { s1 += pz[k]; s2 += pz[k] * pz[k]; }
#pragma unroll
    for (int off = 32; off >= 1; off >>= 1) {
        s1 += __shfl_down(s1, off, 64);
        s2 += __shfl_down(s2, off, 64);
    }
    __shared__ float r1[16], r2[16];
    if (lane == 0) { r1[wid] = s1; r2[wid] = s2; }
    __syncthreads();                          // also makes sel[] fully visible
    float S1 = 0.f, S2 = 0.f;
#pragma unroll
    for (int w = 0; w < 16; w++) { S1 += r1[w]; S2 += r2[w]; }
    float mean = S1 / 8192.0f;
    float var1 = (S2 - S1 * S1 / 8192.0f) / 8191.0f;           // ddof=1
    float sc = 1.0f + expf(-var1 / 0.1f) * 0.9f;               // component safety
    if (t < 256) {
        int p = sel[t];
        float z = cb[p * 3 + 2];
        safety_all[b * 256 + t] = 1.0f + (1.0f / (1.0f + expf(-((z - mean) / 5.0f)))) * 0.95f;
    }
    if (t < 128) safety_all[512 + b * 128 + t] = sc;
}

// ---------------- detail density safety: one block per sampled center ----------------
__global__ __launch_bounds__(256) void density_kernel(const float* __restrict__ coords,
                                                      const int* __restrict__ idx_all,
                                                      float* __restrict__ safety_all) {
#pragma clang fp contract(off)
    const int ci = blockIdx.x & 63;
    const int b  = blockIdx.x >> 6;
    const int t  = threadIdx.x;
    const float* cb = coords + (size_t)b * N_PTS * 3;
    const int p = idx_all[768 + b * 64 + ci];
    const float cx = cb[p * 3], cy = cb[p * 3 + 1], cz = cb[p * 3 + 2];
    const float cc = cx * cx + cy * cy + cz * cz;
    int cnt = 0;
    for (int k = 0; k < 32; k++) {
        int q = t + k * 256;
        float x = cb[q * 3], y = cb[q * 3 + 1], z = cb[q * 3 + 2];
        float pp = x * x + y * y + z * z;
        float dot = cx * x + cy * y + cz * z;
        float d2 = (cc + pp) - 2.0f * dot;   // same formula/order as reference _sqdist
        if (d2 < 0.25f) cnt++;
    }
#pragma unroll
    for (int off = 32; off >= 1; off >>= 1) cnt += __shfl_down(cnt, off, 64);
    __shared__ int rc[4];
    int lane = t & 63, wid = t >> 6;
    if (lane == 0) rc[wid] = cnt;
    __syncthreads();
    if (t == 0) {
        int tot = rc[0] + rc[1] + rc[2] + rc[3];
        safety_all[768 + b * 64 + ci] = 1.0f + ((float)tot / 8192.0f) * 0.95f;
    }
}

// ---------------- per-scale score MLP: 8 centers per block ----------------
__global__ __launch_bounds__(256) void score_kernel(
    const float* __restrict__ feat,
    const float* __restrict__ gW1, const float* __restrict__ gb1,
    const float* __restrict__ gW2, const float* __restrict__ gb2,
    const float* __restrict__ cW1, const float* __restrict__ cb1,
    const float* __restrict__ cW2, const float* __restrict__ cb2,
    const float* __restrict__ dW1, const float* __restrict__ db1,
    const float* __restrict__ dW2, const float* __restrict__ db2,
    const int* __restrict__ idx_all, const float* __restrict__ safety_all,
    float* __restrict__ final_all) {
    int bid = blockIdx.x;
    int b, c0, C, S, off;
    const float *W1, *b1, *W2, *b2;
    if (bid < 64)      { C = 256; S = 16; W1 = gW1; b1 = gb1; W2 = gW2; b2 = gb2; b = bid >> 5; c0 = (bid & 31) * 8; off = 0; }
    else if (bid < 96) { int r = bid - 64; C = 128; S = 16; W1 = cW1; b1 = cb1; W2 = cW2; b2 = cb2; b = r >> 4; c0 = (r & 15) * 8; off = 512; }
    else               { int r = bid - 96; C = 64;  S = 8;  W1 = dW1; b1 = db1; W2 = dW2; b2 = db2; b = r >> 3; c0 = (r & 7) * 8; off = 768; }

    __shared__ float xt[8 * 772];
    __shared__ float h1s[8 * 260];
    __shared__ float ps[8 * 16];
    __shared__ int pid[8];
    const int t = threadIdx.x;
    if (t < 8) pid[t] = idx_all[off + b * C + c0 + t];
    __syncthreads();

    for (int r = 0; r < 8; r++) {
        const float* src = feat + ((size_t)b * N_PTS + pid[r]) * D_FEAT;
        for (int c = t; c < 768; c += 256) xt[r * 772 + c] = src[c];
    }
    __syncthreads();

    {
        int rp = t & 3;
        int jg = t >> 2;
        int r0 = rp * 2;
        if (jg * 4 < C) {
            float4 acc0[4], acc1[4];
#pragma unroll
            for (int a = 0; a < 4; a++) { acc0[a] = make_float4(0, 0, 0, 0); acc1[a] = make_float4(0, 0, 0, 0); }
            for (int k = 0; k < 768; k += 4) {
                float4 x0 = *(const float4*)&xt[r0 * 772 + k];
                float4 x1 = *(const float4*)&xt[(r0 + 1) * 772 + k];
#pragma unroll
                for (int a = 0; a < 4; a++) {
                    int j = jg * 4 + a;
                    float4 w = *(const float4*)&W1[(size_t)j * 768 + k];
                    acc0[a].x = fmaf(w.x, x0.x, acc0[a].x); acc0[a].y = fmaf(w.y, x0.y, acc0[a].y);
                    acc0[a].z = fmaf(w.z, x0.z, acc0[a].z); acc0[a].w = fmaf(w.w, x0.w, acc0[a].w);
                    acc1[a].x = fmaf(w.x, x1.x, acc1[a].x); acc1[a].y = fmaf(w.y, x1.y, acc1[a].y);
                    acc1[a].z = fmaf(w.z, x1.z, acc1[a].z); acc1[a].w = fmaf(w.w, x1.w, acc1[a].w);
                }
            }
#pragma unroll
            for (int a = 0; a < 4; a++) {
                int j = jg * 4 + a;
                float bb = b1[j];
                float v0 = (acc0[a].x + acc0[a].y) + (acc0[a].z + acc0[a].w) + bb;
                float v1 = (acc1[a].x + acc1[a].y) + (acc1[a].z + acc1[a].w) + bb;
                h1s[r0 * 260 + j]       = fmaxf(v0, 0.f);
                h1s[(r0 + 1) * 260 + j] = fmaxf(v1, 0.f);
            }
        }
    }
    __syncthreads();

    if (t < 8 * S) {
        int r = t / S, s = t % S;
        float4 a = make_float4(0, 0, 0, 0);
        for (int k = 0; k < C; k += 4) {
            float4 w = *(const float4*)&W2[s * C + k];
            float4 h = *(const float4*)&h1s[r * 260 + k];
            a.x = fmaf(w.x, h.x, a.x); a.y = fmaf(w.y, h.y, a.y);
            a.z = fmaf(w.z, h.z, a.z); a.w = fmaf(w.w, h.w, a.w);
        }
        float logit = (a.x + a.y) + (a.z + a.w) + b2[s];
        ps[r * 16 + s] = 1.0f / (1.0f + expf(-logit));
    }
    __syncthreads();
    if (t < 8) {
        float m = 0.f;
        for (int s = 0; s < S; s++) m += ps[t * 16 + s];
        m /= (float)S;
        final_all[off + b * C + c0 + t] = m * safety_all[off + b * C + c0 + t];
    }
}

// ---------------- top-k per (scale,batch): single wave ----------------
__global__ __launch_bounds__(64) void topk_kernel(const int* __restrict__ idx_all,
                                                  const float* __restrict__ final_all,
                                                  int* __restrict__ tok_pidx) {
    int bid = blockIdx.x;  // 0..5
    int scale = bid >> 1, b = bid & 1;
    int C = (scale == 0) ? 256 : (scale == 1) ? 128 : 64;
    int S = (scale == 2) ? 8 : 16;
    int off = (scale == 0) ? 0 : (scale == 1) ? 512 : 768;
    int base = (scale == 0) ? 0 : (scale == 1) ? 16 : 32;
    int lane = threadIdx.x;
    float v[4];
#pragma unroll
    for (int j = 0; j < 4; j++) {
        int i = lane + j * 64;
        v[j] = (i < C) ? final_all[off + b * C + i] : -INFINITY;
    }
    for (int s = 0; s < S; s++) {
        float bd = -INFINITY; int bi = 0x7fffffff;
#pragma unroll
        for (int j = 0; j < 4; j++) {
            int i = lane + j * 64;
            if (i < C && v[j] > bd) { bd = v[j]; bi = i; }
        }
        for (int m = 1; m < 64; m <<= 1) {
            float odv = __shfl_xor(bd, m, 64);
            int   oiv = __shfl_xor(bi, m, 64);
            if (odv > bd || (odv == bd && oiv < bi)) { bd = odv; bi = oiv; }
        }
#pragma unroll
        for (int j = 0; j < 4; j++)
            if ((bi >> 6) == j && lane == (bi & 63)) v[j] = -INFINITY;
        if (lane == 0) tok_pidx[b * 40 + base + s] = idx_all[off + b * C + bi];
    }
}

// ---------------- final MLP + LayerNorm: 2 tokens per block ----------------
__global__ __launch_bounds__(256) void final_kernel(
    const float* __restrict__ feat, const int* __restrict__ tok_pidx,
    const float* __restrict__ pW1, const float* __restrict__ pb1,
    const float* __restrict__ pW2, const float* __restrict__ pb2,
    const float* __restrict__ lng, const float* __restrict__ lnb,
    float* __restrict__ out) {
    int bid = blockIdx.x;               // 40 blocks
    int b = bid / 20, pr = bid % 20;
    int t = threadIdx.x;
    __shared__ float xt[2 * 772];
    __shared__ float h1s[2 * 388];
    __shared__ float red[16];

    for (int r = 0; r < 2; r++) {
        int tok = pr * 2 + r;
        int p = tok_pidx[b * 40 + tok];
        const float* src = feat + ((size_t)b * N_PTS + p) * D_FEAT;
        for (int c = t; c < 768; c += 256) xt[r * 772 + c] = src[c];
    }
    __syncthreads();

    for (int u = t; u < 768; u += 256) {
        int j = u >> 1, r = u & 1;
        float4 a = make_float4(0, 0, 0, 0);
        for (int k = 0; k < 768; k += 4) {
            float4 w = *(const float4*)&pW1[(size_t)j * 768 + k];
            float4 x = *(const float4*)&xt[r * 772 + k];
            a.x = fmaf(w.x, x.x, a.x); a.y = fmaf(w.y, x.y, a.y);
            a.z = fmaf(w.z, x.z, a.z); a.w = fmaf(w.w, x.w, a.w);
        }
        float v = (a.x + a.y) + (a.z + a.w) + pb1[j];
        h1s[r * 388 + j] = fmaxf(v, 0.f);
    }
    __syncthreads();

    for (int u = t; u < 1536; u += 256) {
        int o = u >> 1, r = u & 1;
        float4 a = make_float4(0, 0, 0, 0);
        for (int k = 0; k < 384; k += 4) {
            float4 w = *(const float4*)&pW2[(size_t)o * 384 + k];
            float4 h = *(const float4*)&h1s[r * 388 + k];
            a.x = fmaf(w.x, h.x, a.x); a.y = fmaf(w.y, h.y, a.y);
            a.z = fmaf(w.z, h.z, a.z); a.w = fmaf(w.w, h.w, a.w);
        }
        xt[r * 772 + o] = (a.x + a.y) + (a.z + a.w) + pb2[o];
    }
    __syncthreads();

    for (int r = 0; r < 2; r++) {
        float s1 = 0.f, s2 = 0.f;
        for (int o = t; o < 768; o += 256) { float v = xt[r * 772 + o]; s1 += v; s2 += v * v; }
#pragma unroll
        for (int off2 = 32; off2 >= 1; off2 >>= 1) {
            s1 += __shfl_down(s1, off2, 64);
            s2 += __shfl_down(s2, off2, 64);
        }
        int lane = t & 63, wid = t >> 6;
        if (lane == 0) { red[wid * 2] = s1; red[wid * 2 + 1] = s2; }
        __syncthreads();
        float S1 = red[0] + red[2] + red[4] + red[6];
        float S2 = red[1] + red[3] + red[5] + red[7];
        float mu = S1 / 768.0f;
        float var = S2 / 768.0f - mu * mu;
        float inv = rsqrtf(var + 1e-5f);
        int tok = pr * 2 + r;
        float* dst = out + ((size_t)b * 40 + tok) * 768;
        for (int o = t; o < 768; o += 256) {
            float v = xt[r * 772 + o];
            dst[o] = (v - mu) * inv * lng[o] + lnb[o];
        }
        __syncthreads();
    }
}

extern "C" void kernel_launch(void* const* d_in, const int* in_sizes, int n_in,
                              void* d_out, int out_size, void* d_ws, size_t ws_size,
                              hipStream_t stream) {
    const float* feat   = (const float*)d_in[0];
    const float* coords = (const float*)d_in[1];
    const float* gW1 = (const float*)d_in[2],  *gb1 = (const float*)d_in[3];
    const float* gW2 = (const float*)d_in[4],  *gb2 = (const float*)d_in[5];
    const float* cW1 = (const float*)d_in[6],  *cb1 = (const float*)d_in[7];
    const float* cW2 = (const float*)d_in[8],  *cb2 = (const float*)d_in[9];
    const float* dW1 = (const float*)d_in[10], *db1 = (const float*)d_in[11];
    const float* dW2 = (const float*)d_in[12], *db2 = (const float*)d_in[13];
    const float* pW1 = (const float*)d_in[14], *pb1 = (const float*)d_in[15];
    const float* pW2 = (const float*)d_in[16], *pb2 = (const float*)d_in[17];
    const float* lng = (const float*)d_in[18], *lnb = (const float*)d_in[19];
    float* out = (float*)d_out;

    int*   idx_all    = (int*)d_ws;
    float* safety_all = (float*)d_ws + 896;
    float* final_all  = (float*)d_ws + 1792;
    int*   tok_pidx   = (int*)d_ws + 2688;

    fps_kernel<<<2, 1024, 0, stream>>>(coords, idx_all, safety_all);
    density_kernel<<<128, 256, 0, stream>>>(coords, idx_all, safety_all);
    score_kernel<<<112, 256, 0, stream>>>(feat, gW1, gb1, gW2, gb2, cW1, cb1, cW2, cb2,
                                          dW1, db1, dW2, db2, idx_all, safety_all, final_all);
    topk_kernel<<<6, 64, 0, stream>>>(idx_all, final_all, tok_pidx);
    final_kernel<<<40, 256, 0, stream>>>(feat, tok_pidx, pW1, pb1, pW2, pb2, lng, lnb, out);
}

// Round 4
// 802.790 us; speedup vs baseline: 1.1978x; 1.1978x over previous
//
#include <hip/hip_runtime.h>
#include <math.h>

#define N_PTS 8192
#define D_FEAT 768

// ---- wave64 reductions via DPP (row_shr 1,2,4,8 + row_bcast15, row_bcast31) ----
// VALU-pipe (~2cyc/step) instead of ds_bpermute (~60cyc/step). Result valid in
// lane 63, broadcast to all lanes via readlane. Identity passed as `old` for
// lanes excluded by row_mask / invalid DPP sources (bound_ctrl=false).
__device__ __forceinline__ float wred_max_f32(float x) {   // x >= 0 required (identity 0)
    int v = __float_as_int(x), o;
    o = __builtin_amdgcn_update_dpp(0, v, 0x111, 0xf, 0xf, false); v = __float_as_int(fmaxf(__int_as_float(v), __int_as_float(o)));
    o = __builtin_amdgcn_update_dpp(0, v, 0x112, 0xf, 0xf, false); v = __float_as_int(fmaxf(__int_as_float(v), __int_as_float(o)));
    o = __builtin_amdgcn_update_dpp(0, v, 0x114, 0xf, 0xf, false); v = __float_as_int(fmaxf(__int_as_float(v), __int_as_float(o)));
    o = __builtin_amdgcn_update_dpp(0, v, 0x118, 0xf, 0xf, false); v = __float_as_int(fmaxf(__int_as_float(v), __int_as_float(o)));
    o = __builtin_amdgcn_update_dpp(0, v, 0x142, 0xa, 0xf, false); v = __float_as_int(fmaxf(__int_as_float(v), __int_as_float(o)));
    o = __builtin_amdgcn_update_dpp(0, v, 0x143, 0xc, 0xf, false); v = __float_as_int(fmaxf(__int_as_float(v), __int_as_float(o)));
    return __int_as_float(__builtin_amdgcn_readlane(v, 63));
}
__device__ __forceinline__ int wred_min_i32(int x) {       // x >= 0 (identity INT_MAX)
    int v = x, o;
    o = __builtin_amdgcn_update_dpp(0x7fffffff, v, 0x111, 0xf, 0xf, false); v = (o < v) ? o : v;
    o = __builtin_amdgcn_update_dpp(0x7fffffff, v, 0x112, 0xf, 0xf, false); v = (o < v) ? o : v;
    o = __builtin_amdgcn_update_dpp(0x7fffffff, v, 0x114, 0xf, 0xf, false); v = (o < v) ? o : v;
    o = __builtin_amdgcn_update_dpp(0x7fffffff, v, 0x118, 0xf, 0xf, false); v = (o < v) ? o : v;
    o = __builtin_amdgcn_update_dpp(0x7fffffff, v, 0x142, 0xa, 0xf, false); v = (o < v) ? o : v;
    o = __builtin_amdgcn_update_dpp(0x7fffffff, v, 0x143, 0xc, 0xf, false); v = (o < v) ? o : v;
    return __builtin_amdgcn_readlane(v, 63);
}
__device__ __forceinline__ float wred_add_f32(float x) {   // identity 0
    int v = __float_as_int(x), o;
    o = __builtin_amdgcn_update_dpp(0, v, 0x111, 0xf, 0xf, false); v = __float_as_int(__int_as_float(v) + __int_as_float(o));
    o = __builtin_amdgcn_update_dpp(0, v, 0x112, 0xf, 0xf, false); v = __float_as_int(__int_as_float(v) + __int_as_float(o));
    o = __builtin_amdgcn_update_dpp(0, v, 0x114, 0xf, 0xf, false); v = __float_as_int(__int_as_float(v) + __int_as_float(o));
    o = __builtin_amdgcn_update_dpp(0, v, 0x118, 0xf, 0xf, false); v = __float_as_int(__int_as_float(v) + __int_as_float(o));
    o = __builtin_amdgcn_update_dpp(0, v, 0x142, 0xa, 0xf, false); v = __float_as_int(__int_as_float(v) + __int_as_float(o));
    o = __builtin_amdgcn_update_dpp(0, v, 0x143, 0xc, 0xf, false); v = __float_as_int(__int_as_float(v) + __int_as_float(o));
    return __int_as_float(__builtin_amdgcn_readlane(v, 63));
}

// ---------------- FPS + global/component safety: one block per batch ----------------
// FPS is prefix-consistent in num_samples: one 256-step run serves all scales.
// idx layout: g[0,512) c[512,768) d[768,896)
__global__ __launch_bounds__(512, 1) void fps_kernel(const float* __restrict__ coords,
                                                     int* __restrict__ idx_all,
                                                     float* __restrict__ safety_all) {
#pragma clang fp contract(off)
    const int b = blockIdx.x;         // 0..1
    const int t = threadIdx.x;
    const float* cb = coords + (size_t)b * N_PTS * 3;
    int* og = idx_all + b * 256;
    int* oc = idx_all + 512 + b * 128;
    int* od = idx_all + 768 + b * 64;

    float px[16], py[16], pz[16], dist[16], ub[16];
#pragma unroll
    for (int k = 0; k < 16; k++) {
        int p = t + k * 512;
        px[k] = cb[p * 3 + 0];
        py[k] = cb[p * 3 + 1];
        pz[k] = cb[p * 3 + 2];
        dist[k] = INFINITY; ub[k] = INFINITY;
    }
    __shared__ float swmax[2][8];
    __shared__ int   swcand[2][8];
    __shared__ float scw[2][8][3];    // per-wave candidate coords (parity-buffered)
    __shared__ int   sel[256];
    __shared__ float r1s[8], r2s[8];
    if (t == 0) { og[0] = 0; oc[0] = 0; od[0] = 0; sel[0] = 0; }
    float lx = cb[0], ly = cb[1], lz = cb[2];   // center 0, uniform broadcast load
    __syncthreads();

    const int lane = t & 63, w = t >> 6;
    for (int i = 1; i < 256; i++) {
#pragma unroll
        for (int k = 0; k < 16; k++) {
            float dx = px[k] - lx, dy = py[k] - ly, dz = pz[k] - lz;
            float d2 = dx * dx + dy * dy + dz * dz;   // contract off: numpy op order
            // conservative sqrt-skip: margin (1+2e-6) > (1+ulp)^3, no false negatives
            if (__any(d2 < ub[k])) {
                float d = sqrtf(d2);                  // correctly rounded = np.sqrt
                float nd = fminf(dist[k], d);
                dist[k] = nd;
                ub[k] = nd * nd * 1.000002f;
            }
        }
        // per-thread argmax: ascending k => smallest global idx kept on ties
        float bd = dist[0]; int bk = 0;
#pragma unroll
        for (int k = 1; k < 16; k++) if (dist[k] > bd) { bd = dist[k]; bk = k; }
        int bi = t + bk * 512;
        // wave argmax: max value, then min index among achievers (DPP, VALU-pipe)
        float m = wred_max_f32(bd);
        int cand = (bd == m) ? bi : 0x7fffffff;
        int cmin = wred_min_i32(cand);
        if (lane == 0) { swmax[i & 1][w] = m; swcand[i & 1][w] = cmin; }
        // wave-candidate owner stashes its coords (pre-barrier; owner is in this wave)
        if (t == (cmin & 511)) {
            int kk = cmin >> 9;
            float wx = 0.f, wy = 0.f, wz = 0.f;
#pragma unroll
            for (int k = 0; k < 16; k++) if (k == kk) { wx = px[k]; wy = py[k]; wz = pz[k]; }
            scw[i & 1][w][0] = wx; scw[i & 1][w][1] = wy; scw[i & 1][w][2] = wz;
        }
        __syncthreads();   // single barrier/iter; parity buffers prevent WAR hazard
        const int par = i & 1;
        float bm = swmax[par][0];
#pragma unroll
        for (int w2 = 1; w2 < 8; w2++) bm = fmaxf(bm, swmax[par][w2]);
        int fbi = 0x7fffffff;
#pragma unroll
        for (int w2 = 0; w2 < 8; w2++) {
            int c2 = (swmax[par][w2] == bm) ? swcand[par][w2] : 0x7fffffff;
            fbi = (c2 < fbi) ? c2 : fbi;
        }
        int ww = 0;        // unique: fbi's owner thread lives in exactly one wave
#pragma unroll
        for (int w2 = 0; w2 < 8; w2++) if (swcand[par][w2] == fbi) ww = w2;
        lx = scw[par][ww][0]; ly = scw[par][ww][1]; lz = scw[par][ww][2];
        if (t == (fbi & 511)) {
            int kk = fbi >> 9;
#pragma unroll
            for (int k = 0; k < 16; k++) if (k == kk) { dist[k] = 0.f; ub[k] = 0.f; }
        }
        if (t == 0) {
            sel[i] = fbi; og[i] = fbi;
            if (i < 128) oc[i] = fbi;
            if (i < 64)  od[i] = fbi;
        }
    }

    // ---- tail: global & component safety (z already in registers) ----
    float s1 = 0.f, s2 = 0.f;
#pragma unroll
    for (int k = 0; k < 16; k++) { s1 += pz[k]; s2 += pz[k] * pz[k]; }
    s1 = wred_add_f32(s1);
    s2 = wred_add_f32(s2);
    if (lane == 0) { r1s[w] = s1; r2s[w] = s2; }
    __syncthreads();                        // also makes sel[] fully visible
    float S1 = 0.f, S2 = 0.f;
#pragma unroll
    for (int w2 = 0; w2 < 8; w2++) { S1 += r1s[w2]; S2 += r2s[w2]; }
    float mean = S1 / 8192.0f;
    float var1 = (S2 - S1 * S1 / 8192.0f) / 8191.0f;     // ddof=1
    float scomp = 1.0f + expf(-var1 / 0.1f) * 0.9f;      // component safety
    if (t < 256) {
        int p = sel[t];
        float z = cb[p * 3 + 2];
        safety_all[b * 256 + t] = 1.0f + (1.0f / (1.0f + expf(-((z - mean) / 5.0f)))) * 0.95f;
    }
    if (t < 128) safety_all[512 + b * 128 + t] = scomp;
}

// ---------------- per-scale score MLP (+ detail density folded in) ----------------
// grid: g blocks [0,64), c [64,96), d [96,112). Detail blocks compute their own
// 8 densities in-block (no cross-block dependency) -> density launch eliminated.
__global__ __launch_bounds__(256) void score_kernel(
    const float* __restrict__ feat, const float* __restrict__ coords,
    const float* __restrict__ gW1, const float* __restrict__ gb1,
    const float* __restrict__ gW2, const float* __restrict__ gb2,
    const float* __restrict__ cW1, const float* __restrict__ cb1,
    const float* __restrict__ cW2, const float* __restrict__ cb2,
    const float* __restrict__ dW1, const float* __restrict__ db1,
    const float* __restrict__ dW2, const float* __restrict__ db2,
    const int* __restrict__ idx_all, const float* __restrict__ safety_all,
    float* __restrict__ final_all) {
    int bid = blockIdx.x;
    int b, c0, C, S, off;
    const float *W1, *b1, *W2, *b2;
    if (bid < 64)      { C = 256; S = 16; W1 = gW1; b1 = gb1; W2 = gW2; b2 = gb2; b = bid >> 5; c0 = (bid & 31) * 8; off = 0; }
    else if (bid < 96) { int r = bid - 64; C = 128; S = 16; W1 = cW1; b1 = cb1; W2 = cW2; b2 = cb2; b = r >> 4; c0 = (r & 15) * 8; off = 512; }
    else               { int r = bid - 96; C = 64;  S = 8;  W1 = dW1; b1 = db1; W2 = dW2; b2 = db2; b = r >> 3; c0 = (r & 7) * 8; off = 768; }
    const bool isdet = (bid >= 96);

    __shared__ float xt[8 * 772];
    __shared__ float h1s[8 * 260];
    __shared__ float ps[8 * 16];
    __shared__ int pid[8];
    __shared__ float dpart[4][8];
    __shared__ float sdens[8];
    const int t = threadIdx.x;
    if (t < 8) pid[t] = idx_all[off + b * C + c0 + t];
    __syncthreads();

    if (isdet) {
#pragma clang fp contract(off)
        float cx[8], cy[8], cz[8], cc[8];
#pragma unroll
        for (int c = 0; c < 8; c++) {
            const float* cp = coords + ((size_t)b * N_PTS + pid[c]) * 3;
            cx[c] = cp[0]; cy[c] = cp[1]; cz[c] = cp[2];
            cc[c] = cx[c] * cx[c] + cy[c] * cy[c] + cz[c] * cz[c];
        }
        int cnt[8];
#pragma unroll
        for (int c = 0; c < 8; c++) cnt[c] = 0;
        const float* cbl = coords + (size_t)b * N_PTS * 3;
        for (int k = 0; k < 32; k++) {
            int q = t + k * 256;
            float x = cbl[q * 3], y = cbl[q * 3 + 1], z = cbl[q * 3 + 2];
            float pp = x * x + y * y + z * z;
#pragma unroll
            for (int c = 0; c < 8; c++) {
                float dot = cx[c] * x + cy[c] * y + cz[c] * z;
                float d2 = (cc[c] + pp) - 2.0f * dot;   // same formula/order as reference
                if (d2 < 0.25f) cnt[c]++;
            }
        }
        int wv = t >> 6;
#pragma unroll
        for (int c = 0; c < 8; c++) {
            float s = wred_add_f32((float)cnt[c]);      // integer counts: exact in f32
            if ((t & 63) == 0) dpart[wv][c] = s;
        }
    }

    for (int r = 0; r < 8; r++) {
        const float* src = feat + ((size_t)b * N_PTS + pid[r]) * D_FEAT;
        for (int c = t; c < 768; c += 256) xt[r * 772 + c] = src[c];
    }
    __syncthreads();
    if (isdet && t < 8) {
        float tot = dpart[0][t] + dpart[1][t] + dpart[2][t] + dpart[3][t];
        sdens[t] = 1.0f + (tot / 8192.0f) * 0.95f;
    }

    {
        int rp = t & 3;
        int jg = t >> 2;
        int r0 = rp * 2;
        if (jg * 4 < C) {
            float4 acc0[4], acc1[4];
#pragma unroll
            for (int a = 0; a < 4; a++) { acc0[a] = make_float4(0, 0, 0, 0); acc1[a] = make_float4(0, 0, 0, 0); }
            for (int k = 0; k < 768; k += 4) {
                float4 x0 = *(const float4*)&xt[r0 * 772 + k];
                float4 x1 = *(const float4*)&xt[(r0 + 1) * 772 + k];
#pragma unroll
                for (int a = 0; a < 4; a++) {
                    int j = jg * 4 + a;
                    float4 wv = *(const float4*)&W1[(size_t)j * 768 + k];
                    acc0[a].x = fmaf(wv.x, x0.x, acc0[a].x); acc0[a].y = fmaf(wv.y, x0.y, acc0[a].y);
                    acc0[a].z = fmaf(wv.z, x0.z, acc0[a].z); acc0[a].w = fmaf(wv.w, x0.w, acc0[a].w);
                    acc1[a].x = fmaf(wv.x, x1.x, acc1[a].x); acc1[a].y = fmaf(wv.y, x1.y, acc1[a].y);
                    acc1[a].z = fmaf(wv.z, x1.z, acc1[a].z); acc1[a].w = fmaf(wv.w, x1.w, acc1[a].w);
                }
            }
#pragma unroll
            for (int a = 0; a < 4; a++) {
                int j = jg * 4 + a;
                float bb = b1[j];
                float v0 = (acc0[a].x + acc0[a].y) + (acc0[a].z + acc0[a].w) + bb;
                float v1 = (acc1[a].x + acc1[a].y) + (acc1[a].z + acc1[a].w) + bb;
                h1s[r0 * 260 + j]       = fmaxf(v0, 0.f);
                h1s[(r0 + 1) * 260 + j] = fmaxf(v1, 0.f);
            }
        }
    }
    __syncthreads();

    if (t < 8 * S) {
        int r = t / S, s = t % S;
        float4 a = make_float4(0, 0, 0, 0);
        for (int k = 0; k < C; k += 4) {
            float4 wv = *(const float4*)&W2[s * C + k];
            float4 h = *(const float4*)&h1s[r * 260 + k];
            a.x = fmaf(wv.x, h.x, a.x); a.y = fmaf(wv.y, h.y, a.y);
            a.z = fmaf(wv.z, h.z, a.z); a.w = fmaf(wv.w, h.w, a.w);
        }
        float logit = (a.x + a.y) + (a.z + a.w) + b2[s];
        ps[r * 16 + s] = 1.0f / (1.0f + expf(-logit));
    }
    __syncthreads();
    if (t < 8) {
        float m = 0.f;
        for (int s = 0; s < S; s++) m += ps[t * 16 + s];
        m /= (float)S;
        float saf = isdet ? sdens[t] : safety_all[off + b * C + c0 + t];
        final_all[off + b * C + c0 + t] = m * saf;
    }
}

// ---------------- final MLP + LayerNorm, with per-block redundant top-k ----------------
// 40 blocks; each block handles 2 tokens, which never straddle a scale boundary,
// so each block recomputes its own scale's top-k (tiny: <=16 DPP-argmax rounds).
__global__ __launch_bounds__(256) void final_kernel(
    const float* __restrict__ feat, const int* __restrict__ idx_all,
    const float* __restrict__ final_all,
    const float* __restrict__ pW1, const float* __restrict__ pb1,
    const float* __restrict__ pW2, const float* __restrict__ pb2,
    const float* __restrict__ lng, const float* __restrict__ lnb,
    float* __restrict__ out) {
    int bid = blockIdx.x;               // 40 blocks
    int b = bid / 20, pr = bid % 20;
    int t = threadIdx.x;
    __shared__ float xt[2 * 772];
    __shared__ float h1s[2 * 388];
    __shared__ float red[16];
    __shared__ int tokp[2];

    int scale = (pr < 8) ? 0 : (pr < 16) ? 1 : 2;
    int C    = (scale == 0) ? 256 : (scale == 1) ? 128 : 64;
    int off  = (scale == 0) ? 0 : (scale == 1) ? 512 : 768;
    int base = (scale == 0) ? 0 : (scale == 1) ? 8 : 16;   // in block units
    int r0 = (pr - base) * 2;           // rank of first token within scale

    if (t < 64) {                       // wave 0 does the top-k
        float v[4];
#pragma unroll
        for (int j = 0; j < 4; j++) {
            int ii = t + j * 64;
            v[j] = (ii < C) ? final_all[off + b * C + ii] : -INFINITY;
        }
        for (int s = 0; s <= r0 + 1; s++) {
            float bd = v[0]; int bj = 0;
#pragma unroll
            for (int j = 1; j < 4; j++) if (v[j] > bd) { bd = v[j]; bj = j; }
            int bi2 = t + bj * 64;
            float m = wred_max_f32(bd);          // scores > 0, identity 0 safe
            int cand = (bd == m) ? bi2 : 0x7fffffff;
            int wi = wred_min_i32(cand);         // first-index tie-break = lax.top_k
            if (t == (wi & 63)) {
#pragma unroll
                for (int j = 0; j < 4; j++) if (j == (wi >> 6)) v[j] = -INFINITY;
            }
            if (t == 0) {
                if (s == r0)     tokp[0] = idx_all[off + b * C + wi];
                if (s == r0 + 1) tokp[1] = idx_all[off + b * C + wi];
            }
        }
    }
    __syncthreads();

    for (int r = 0; r < 2; r++) {
        int p = tokp[r];
        const float* src = feat + ((size_t)b * N_PTS + p) * D_FEAT;
        for (int c = t; c < 768; c += 256) xt[r * 772 + c] = src[c];
    }
    __syncthreads();

    for (int u = t; u < 768; u += 256) {
        int j = u >> 1, r = u & 1;
        float4 a = make_float4(0, 0, 0, 0);
        for (int k = 0; k < 768; k += 4) {
            float4 wv = *(const float4*)&pW1[(size_t)j * 768 + k];
            float4 x = *(const float4*)&xt[r * 772 + k];
            a.x = fmaf(wv.x, x.x, a.x); a.y = fmaf(wv.y, x.y, a.y);
            a.z = fmaf(wv.z, x.z, a.z); a.w = fmaf(wv.w, x.w, a.w);
        }
        float v = (a.x + a.y) + (a.z + a.w) + pb1[j];
        h1s[r * 388 + j] = fmaxf(v, 0.f);
    }
    __syncthreads();

    for (int u = t; u < 1536; u += 256) {
        int o = u >> 1, r = u & 1;
        float4 a = make_float4(0, 0, 0, 0);
        for (int k = 0; k < 384; k += 4) {
            float4 wv = *(const float4*)&pW2[(size_t)o * 384 + k];
            float4 h = *(const float4*)&h1s[r * 388 + k];
            a.x = fmaf(wv.x, h.x, a.x); a.y = fmaf(wv.y, h.y, a.y);
            a.z = fmaf(wv.z, h.z, a.z); a.w = fmaf(wv.w, h.w, a.w);
        }
        xt[r * 772 + o] = (a.x + a.y) + (a.z + a.w) + pb2[o];
    }
    __syncthreads();

    for (int r = 0; r < 2; r++) {
        float s1 = 0.f, s2 = 0.f;
        for (int o = t; o < 768; o += 256) { float v = xt[r * 772 + o]; s1 += v; s2 += v * v; }
#pragma unroll
        for (int off2 = 32; off2 >= 1; off2 >>= 1) {
            s1 += __shfl_down(s1, off2, 64);
            s2 += __shfl_down(s2, off2, 64);
        }
        int lane = t & 63, wid = t >> 6;
        if (lane == 0) { red[wid * 2] = s1; red[wid * 2 + 1] = s2; }
        __syncthreads();
        float S1 = red[0] + red[2] + red[4] + red[6];
        float S2 = red[1] + red[3] + red[5] + red[7];
        float mu = S1 / 768.0f;
        float var = S2 / 768.0f - mu * mu;
        float inv = rsqrtf(var + 1e-5f);
        float* dst = out + ((size_t)b * 40 + pr * 2 + r) * 768;
        for (int o = t; o < 768; o += 256) {
            float v = xt[r * 772 + o];
            dst[o] = (v - mu) * inv * lng[o] + lnb[o];
        }
        __syncthreads();
    }
}

extern "C" void kernel_launch(void* const* d_in, const int* in_sizes, int n_in,
                              void* d_out, int out_size, void* d_ws, size_t ws_size,
                              hipStream_t stream) {
    const float* feat   = (const float*)d_in[0];
    const float* coords = (const float*)d_in[1];
    const float* gW1 = (const float*)d_in[2],  *gb1 = (const float*)d_in[3];
    const float* gW2 = (const float*)d_in[4],  *gb2 = (const float*)d_in[5];
    const float* cW1 = (const float*)d_in[6],  *cb1 = (const float*)d_in[7];
    const float* cW2 = (const float*)d_in[8],  *cb2 = (const float*)d_in[9];
    const float* dW1 = (const float*)d_in[10], *db1 = (const float*)d_in[11];
    const float* dW2 = (const float*)d_in[12], *db2 = (const float*)d_in[13];
    const float* pW1 = (const float*)d_in[14], *pb1 = (const float*)d_in[15];
    const float* pW2 = (const float*)d_in[16], *pb2 = (const float*)d_in[17];
    const float* lng = (const float*)d_in[18], *lnb = (const float*)d_in[19];
    float* out = (float*)d_out;

    int*   idx_all    = (int*)d_ws;               // 896 ints
    float* safety_all = (float*)d_ws + 896;       // 768 floats used
    float* final_all  = (float*)d_ws + 1792;      // 896 floats

    fps_kernel<<<2, 512, 0, stream>>>(coords, idx_all, safety_all);
    score_kernel<<<112, 256, 0, stream>>>(feat, coords, gW1, gb1, gW2, gb2, cW1, cb1, cW2, cb2,
                                          dW1, db1, dW2, db2, idx_all, safety_all, final_all);
    final_kernel<<<40, 256, 0, stream>>>(feat, idx_all, final_all, pW1, pb1, pW2, pb2, lng, lnb, out);
}

// Round 5
// 733.531 us; speedup vs baseline: 1.3109x; 1.0944x over previous
//
#include <hip/hip_runtime.h>
#include <math.h>

#define N_PTS 8192
#define D_FEAT 768

// ---- wave64 reductions via DPP (row_shr 1,2,4,8 + row_bcast15, row_bcast31) ----
__device__ __forceinline__ float wred_max_f32(float x) {   // x >= 0 required (identity 0)
    int v = __float_as_int(x), o;
    o = __builtin_amdgcn_update_dpp(0, v, 0x111, 0xf, 0xf, false); v = __float_as_int(fmaxf(__int_as_float(v), __int_as_float(o)));
    o = __builtin_amdgcn_update_dpp(0, v, 0x112, 0xf, 0xf, false); v = __float_as_int(fmaxf(__int_as_float(v), __int_as_float(o)));
    o = __builtin_amdgcn_update_dpp(0, v, 0x114, 0xf, 0xf, false); v = __float_as_int(fmaxf(__int_as_float(v), __int_as_float(o)));
    o = __builtin_amdgcn_update_dpp(0, v, 0x118, 0xf, 0xf, false); v = __float_as_int(fmaxf(__int_as_float(v), __int_as_float(o)));
    o = __builtin_amdgcn_update_dpp(0, v, 0x142, 0xa, 0xf, false); v = __float_as_int(fmaxf(__int_as_float(v), __int_as_float(o)));
    o = __builtin_amdgcn_update_dpp(0, v, 0x143, 0xc, 0xf, false); v = __float_as_int(fmaxf(__int_as_float(v), __int_as_float(o)));
    return __int_as_float(__builtin_amdgcn_readlane(v, 63));
}
__device__ __forceinline__ int wred_min_i32(int x) {       // x >= 0 (identity INT_MAX)
    int v = x, o;
    o = __builtin_amdgcn_update_dpp(0x7fffffff, v, 0x111, 0xf, 0xf, false); v = (o < v) ? o : v;
    o = __builtin_amdgcn_update_dpp(0x7fffffff, v, 0x112, 0xf, 0xf, false); v = (o < v) ? o : v;
    o = __builtin_amdgcn_update_dpp(0x7fffffff, v, 0x114, 0xf, 0xf, false); v = (o < v) ? o : v;
    o = __builtin_amdgcn_update_dpp(0x7fffffff, v, 0x118, 0xf, 0xf, false); v = (o < v) ? o : v;
    o = __builtin_amdgcn_update_dpp(0x7fffffff, v, 0x142, 0xa, 0xf, false); v = (o < v) ? o : v;
    o = __builtin_amdgcn_update_dpp(0x7fffffff, v, 0x143, 0xc, 0xf, false); v = (o < v) ? o : v;
    return __builtin_amdgcn_readlane(v, 63);
}
__device__ __forceinline__ float wred_add_f32(float x) {   // identity 0
    int v = __float_as_int(x), o;
    o = __builtin_amdgcn_update_dpp(0, v, 0x111, 0xf, 0xf, false); v = __float_as_int(__int_as_float(v) + __int_as_float(o));
    o = __builtin_amdgcn_update_dpp(0, v, 0x112, 0xf, 0xf, false); v = __float_as_int(__int_as_float(v) + __int_as_float(o));
    o = __builtin_amdgcn_update_dpp(0, v, 0x114, 0xf, 0xf, false); v = __float_as_int(__int_as_float(v) + __int_as_float(o));
    o = __builtin_amdgcn_update_dpp(0, v, 0x118, 0xf, 0xf, false); v = __float_as_int(__int_as_float(v) + __int_as_float(o));
    o = __builtin_amdgcn_update_dpp(0, v, 0x142, 0xa, 0xf, false); v = __float_as_int(__int_as_float(v) + __int_as_float(o));
    o = __builtin_amdgcn_update_dpp(0, v, 0x143, 0xc, 0xf, false); v = __float_as_int(__int_as_float(v) + __int_as_float(o));
    return __int_as_float(__builtin_amdgcn_readlane(v, 63));
}

// u64 max-merge DPP step on (hi,lo) pair. identity (0,0) loses to any real key.
#define DPP64_MAX_STEP(ctrl, rmask)                                                       \
    {                                                                                     \
        unsigned ohi = (unsigned)__builtin_amdgcn_update_dpp(0, (int)hi, ctrl, rmask, 0xf, false); \
        unsigned olo = (unsigned)__builtin_amdgcn_update_dpp(0, (int)lo, ctrl, rmask, 0xf, false); \
        bool gt = (ohi > hi) || ((ohi == hi) && (olo > lo));                              \
        hi = gt ? ohi : hi;                                                               \
        lo = gt ? olo : lo;                                                               \
    }

// ---------------- FPS + global/component safety: one block per batch ----------------
// d2-domain min maintenance: correctly-rounded sqrt is monotone, so
// sqrt_r(min d2) == min(sqrt_r(d2)) exactly -> no sqrt in the 16-step update.
// Argmax key packs (sqrt_bits<<32)|~idx so u64-max = (max value, first index),
// matching jnp.argmax tie-break exactly (incl. sqrt rounding-collapse ties,
// via the rare exact path when >=2 d2 values sit within a 5e-7 band).
__global__ __launch_bounds__(512, 1) void fps_kernel(const float* __restrict__ coords,
                                                     int* __restrict__ idx_all,
                                                     float* __restrict__ safety_all) {
#pragma clang fp contract(off)
    const int b = blockIdx.x;         // 0..1
    const int t = threadIdx.x;
    const float* cb = coords + (size_t)b * N_PTS * 3;
    int* og = idx_all + b * 256;
    int* oc = idx_all + 512 + b * 128;
    int* od = idx_all + 768 + b * 64;

    float px[16], py[16], pz[16], m2[16];
#pragma unroll
    for (int k = 0; k < 16; k++) {
        int p = t + k * 512;
        px[k] = cb[p * 3 + 0];
        py[k] = cb[p * 3 + 1];
        pz[k] = cb[p * 3 + 2];
        m2[k] = INFINITY;
    }
    __shared__ unsigned long long skey[2][8];
    __shared__ float scw[2][24];      // per-wave candidate coords, flattened w*3+c
    __shared__ int sel[256];
    __shared__ float r1s[8], r2s[8];
    if (t == 0) { og[0] = 0; oc[0] = 0; od[0] = 0; sel[0] = 0; }
    float lx = cb[0], ly = cb[1], lz = cb[2];   // center 0 (uniform broadcast load)
    __syncthreads();

    const int lane = t & 63, w = t >> 6;
    for (int i = 1; i < 256; i++) {
        // --- branch-free d2-domain update: 9 VALU/k, fully pipelineable ---
#pragma unroll
        for (int k = 0; k < 16; k++) {
            float dx = px[k] - lx, dy = py[k] - ly, dz = pz[k] - lz;
            float d2 = dx * dx + dy * dy + dz * dz;   // contract off: numpy op order
            m2[k] = fminf(m2[k], d2);
        }
        // --- per-thread argmax (value + first index), d2 domain ---
        float c2 = m2[0]; int bk = 0;
#pragma unroll
        for (int k = 1; k < 16; k++) if (m2[k] > c2) { c2 = m2[k]; bk = k; }
        // sqrt-collapse guard: if >=2 entries within relative 5e-7 of c2, their
        // rounded sqrts could tie -> exact path. Band > 2*ulp(sqrt) + slop, so
        // outside the band strict d2 order == strict sqrt order.
        int ncnt = 0;
#pragma unroll
        for (int k = 0; k < 16; k++) ncnt += (m2[k] >= c2 * 0.9999995f) ? 1 : 0;
        float smax;
        if (__any(ncnt >= 2)) {       // rare wave-uniform slow path (exact)
            float sd[16];
#pragma unroll
            for (int k = 0; k < 16; k++) sd[k] = sqrtf(m2[k]);
            smax = sd[0]; bk = 0;
#pragma unroll
            for (int k = 1; k < 16; k++) if (sd[k] > smax) { smax = sd[k]; bk = k; }
        } else {
            smax = sqrtf(c2);         // one correctly-rounded sqrt per thread
        }
        int bi = t + bk * 512;
        // --- wave reduce on packed u64 key: (value desc, index asc) ---
        unsigned hi = __float_as_uint(smax);
        unsigned lo = 0xFFFFFFFFu - (unsigned)bi;
        DPP64_MAX_STEP(0x111, 0xf)    // row_shr1
        DPP64_MAX_STEP(0x112, 0xf)    // row_shr2
        DPP64_MAX_STEP(0x114, 0xf)    // row_shr4
        DPP64_MAX_STEP(0x118, 0xf)    // row_shr8
        DPP64_MAX_STEP(0x142, 0xa)    // row_bcast15
        DPP64_MAX_STEP(0x143, 0xc)    // row_bcast31
        unsigned whi = (unsigned)__builtin_amdgcn_readlane((int)hi, 63);
        unsigned wlo = (unsigned)__builtin_amdgcn_readlane((int)lo, 63);
        if (lane == 0) skey[i & 1][w] = ((unsigned long long)whi << 32) | wlo;
        int wcand = (int)(0xFFFFFFFFu - wlo);
        if (t == (wcand & 511)) {     // wave-candidate owner stashes its coords
            int kk = wcand >> 9;
            float wx = 0.f, wy = 0.f, wz = 0.f;
#pragma unroll
            for (int k = 0; k < 16; k++) if (k == kk) { wx = px[k]; wy = py[k]; wz = pz[k]; }
            scw[i & 1][w * 3 + 0] = wx;
            scw[i & 1][w * 3 + 1] = wy;
            scw[i & 1][w * 3 + 2] = wz;
        }
        __syncthreads();   // single barrier/iter; parity buffers prevent WAR hazard
        const int par = i & 1;
        // --- lane-parallel block combine: 1 ds_read_b64 + 3 DPP steps ---
        unsigned long long k8 = skey[par][lane & 7];
        {
            unsigned hi = (unsigned)(k8 >> 32), lo = (unsigned)k8;
            DPP64_MAX_STEP(0x111, 0xf)
            DPP64_MAX_STEP(0x112, 0xf)
            DPP64_MAX_STEP(0x114, 0xf)   // lane 7 now holds max of keys 0..7
            k8 = ((unsigned long long)(unsigned)__builtin_amdgcn_readlane((int)hi, 7) << 32)
               | (unsigned)__builtin_amdgcn_readlane((int)lo, 7);
        }
        int fbi = (int)(0xFFFFFFFFu - (unsigned)(k8 & 0xFFFFFFFFu));
        int ww = (fbi & 511) >> 6;
        // coords: all 24 stash floats were loaded lane-parallel; pick via readlane
        float cval = scw[par][lane < 24 ? lane : 0];
        lx = __int_as_float(__builtin_amdgcn_readlane(__float_as_int(cval), 3 * ww + 0));
        ly = __int_as_float(__builtin_amdgcn_readlane(__float_as_int(cval), 3 * ww + 1));
        lz = __int_as_float(__builtin_amdgcn_readlane(__float_as_int(cval), 3 * ww + 2));
        if (t == (fbi & 511)) {       // zero the picked point (no dynamic reg index)
#pragma unroll
            for (int k = 0; k < 16; k++) if (fbi == t + k * 512) m2[k] = 0.f;
        }
        if (t == 0) {
            sel[i] = fbi; og[i] = fbi;
            if (i < 128) oc[i] = fbi;
            if (i < 64)  od[i] = fbi;
        }
    }

    // ---- tail: global & component safety (z already in registers) ----
    float s1 = 0.f, s2 = 0.f;
#pragma unroll
    for (int k = 0; k < 16; k++) { s1 += pz[k]; s2 += pz[k] * pz[k]; }
    s1 = wred_add_f32(s1);
    s2 = wred_add_f32(s2);
    if (lane == 0) { r1s[w] = s1; r2s[w] = s2; }
    __syncthreads();                        // also makes sel[] fully visible
    float S1 = 0.f, S2 = 0.f;
#pragma unroll
    for (int w2 = 0; w2 < 8; w2++) { S1 += r1s[w2]; S2 += r2s[w2]; }
    float mean = S1 / 8192.0f;
    float var1 = (S2 - S1 * S1 / 8192.0f) / 8191.0f;     // ddof=1
    float scomp = 1.0f + expf(-var1 / 0.1f) * 0.9f;      // component safety
    if (t < 256) {
        int p = sel[t];
        float z = cb[p * 3 + 2];
        safety_all[b * 256 + t] = 1.0f + (1.0f / (1.0f + expf(-((z - mean) / 5.0f)))) * 0.95f;
    }
    if (t < 128) safety_all[512 + b * 128 + t] = scomp;
}

// ---------------- per-scale score MLP (+ detail density folded in) ----------------
__global__ __launch_bounds__(256) void score_kernel(
    const float* __restrict__ feat, const float* __restrict__ coords,
    const float* __restrict__ gW1, const float* __restrict__ gb1,
    const float* __restrict__ gW2, const float* __restrict__ gb2,
    const float* __restrict__ cW1, const float* __restrict__ cb1,
    const float* __restrict__ cW2, const float* __restrict__ cb2,
    const float* __restrict__ dW1, const float* __restrict__ db1,
    const float* __restrict__ dW2, const float* __restrict__ db2,
    const int* __restrict__ idx_all, const float* __restrict__ safety_all,
    float* __restrict__ final_all) {
    int bid = blockIdx.x;
    int b, c0, C, S, off;
    const float *W1, *b1, *W2, *b2;
    if (bid < 64)      { C = 256; S = 16; W1 = gW1; b1 = gb1; W2 = gW2; b2 = gb2; b = bid >> 5; c0 = (bid & 31) * 8; off = 0; }
    else if (bid < 96) { int r = bid - 64; C = 128; S = 16; W1 = cW1; b1 = cb1; W2 = cW2; b2 = cb2; b = r >> 4; c0 = (r & 15) * 8; off = 512; }
    else               { int r = bid - 96; C = 64;  S = 8;  W1 = dW1; b1 = db1; W2 = dW2; b2 = db2; b = r >> 3; c0 = (r & 7) * 8; off = 768; }
    const bool isdet = (bid >= 96);

    __shared__ float xt[8 * 772];
    __shared__ float h1s[8 * 260];
    __shared__ float ps[8 * 16];
    __shared__ int pid[8];
    __shared__ float dpart[4][8];
    __shared__ float sdens[8];
    const int t = threadIdx.x;
    if (t < 8) pid[t] = idx_all[off + b * C + c0 + t];
    __syncthreads();

    if (isdet) {
#pragma clang fp contract(off)
        float cx[8], cy[8], cz[8], cc[8];
#pragma unroll
        for (int c = 0; c < 8; c++) {
            const float* cp = coords + ((size_t)b * N_PTS + pid[c]) * 3;
            cx[c] = cp[0]; cy[c] = cp[1]; cz[c] = cp[2];
            cc[c] = cx[c] * cx[c] + cy[c] * cy[c] + cz[c] * cz[c];
        }
        int cnt[8];
#pragma unroll
        for (int c = 0; c < 8; c++) cnt[c] = 0;
        const float* cbl = coords + (size_t)b * N_PTS * 3;
        for (int k = 0; k < 32; k++) {
            int q = t + k * 256;
            float x = cbl[q * 3], y = cbl[q * 3 + 1], z = cbl[q * 3 + 2];
            float pp = x * x + y * y + z * z;
#pragma unroll
            for (int c = 0; c < 8; c++) {
                float dot = cx[c] * x + cy[c] * y + cz[c] * z;
                float d2 = (cc[c] + pp) - 2.0f * dot;   // same formula/order as reference
                if (d2 < 0.25f) cnt[c]++;
            }
        }
        int wv = t >> 6;
#pragma unroll
        for (int c = 0; c < 8; c++) {
            float s = wred_add_f32((float)cnt[c]);      // integer counts: exact in f32
            if ((t & 63) == 0) dpart[wv][c] = s;
        }
    }

    for (int r = 0; r < 8; r++) {
        const float* src = feat + ((size_t)b * N_PTS + pid[r]) * D_FEAT;
        for (int c = t; c < 768; c += 256) xt[r * 772 + c] = src[c];
    }
    __syncthreads();
    if (isdet && t < 8) {
        float tot = dpart[0][t] + dpart[1][t] + dpart[2][t] + dpart[3][t];
        sdens[t] = 1.0f + (tot / 8192.0f) * 0.95f;
    }

    {
        int rp = t & 3;
        int jg = t >> 2;
        int r0 = rp * 2;
        if (jg * 4 < C) {
            float4 acc0[4], acc1[4];
#pragma unroll
            for (int a = 0; a < 4; a++) { acc0[a] = make_float4(0, 0, 0, 0); acc1[a] = make_float4(0, 0, 0, 0); }
            for (int k = 0; k < 768; k += 4) {
                float4 x0 = *(const float4*)&xt[r0 * 772 + k];
                float4 x1 = *(const float4*)&xt[(r0 + 1) * 772 + k];
#pragma unroll
                for (int a = 0; a < 4; a++) {
                    int j = jg * 4 + a;
                    float4 wv = *(const float4*)&W1[(size_t)j * 768 + k];
                    acc0[a].x = fmaf(wv.x, x0.x, acc0[a].x); acc0[a].y = fmaf(wv.y, x0.y, acc0[a].y);
                    acc0[a].z = fmaf(wv.z, x0.z, acc0[a].z); acc0[a].w = fmaf(wv.w, x0.w, acc0[a].w);
                    acc1[a].x = fmaf(wv.x, x1.x, acc1[a].x); acc1[a].y = fmaf(wv.y, x1.y, acc1[a].y);
                    acc1[a].z = fmaf(wv.z, x1.z, acc1[a].z); acc1[a].w = fmaf(wv.w, x1.w, acc1[a].w);
                }
            }
#pragma unroll
            for (int a = 0; a < 4; a++) {
                int j = jg * 4 + a;
                float bb = b1[j];
                float v0 = (acc0[a].x + acc0[a].y) + (acc0[a].z + acc0[a].w) + bb;
                float v1 = (acc1[a].x + acc1[a].y) + (acc1[a].z + acc1[a].w) + bb;
                h1s[r0 * 260 + j]       = fmaxf(v0, 0.f);
                h1s[(r0 + 1) * 260 + j] = fmaxf(v1, 0.f);
            }
        }
    }
    __syncthreads();

    if (t < 8 * S) {
        int r = t / S, s = t % S;
        float4 a = make_float4(0, 0, 0, 0);
        for (int k = 0; k < C; k += 4) {
            float4 wv = *(const float4*)&W2[s * C + k];
            float4 h = *(const float4*)&h1s[r * 260 + k];
            a.x = fmaf(wv.x, h.x, a.x); a.y = fmaf(wv.y, h.y, a.y);
            a.z = fmaf(wv.z, h.z, a.z); a.w = fmaf(wv.w, h.w, a.w);
        }
        float logit = (a.x + a.y) + (a.z + a.w) + b2[s];
        ps[r * 16 + s] = 1.0f / (1.0f + expf(-logit));
    }
    __syncthreads();
    if (t < 8) {
        float m = 0.f;
        for (int s = 0; s < S; s++) m += ps[t * 16 + s];
        m /= (float)S;
        float saf = isdet ? sdens[t] : safety_all[off + b * C + c0 + t];
        final_all[off + b * C + c0 + t] = m * saf;
    }
}

// ---------------- final MLP + LayerNorm, with per-block redundant top-k ----------------
__global__ __launch_bounds__(256) void final_kernel(
    const float* __restrict__ feat, const int* __restrict__ idx_all,
    const float* __restrict__ final_all,
    const float* __restrict__ pW1, const float* __restrict__ pb1,
    const float* __restrict__ pW2, const float* __restrict__ pb2,
    const float* __restrict__ lng, const float* __restrict__ lnb,
    float* __restrict__ out) {
    int bid = blockIdx.x;               // 40 blocks
    int b = bid / 20, pr = bid % 20;
    int t = threadIdx.x;
    __shared__ float xt[2 * 772];
    __shared__ float h1s[2 * 388];
    __shared__ float red[16];
    __shared__ int tokp[2];

    int scale = (pr < 8) ? 0 : (pr < 16) ? 1 : 2;
    int C    = (scale == 0) ? 256 : (scale == 1) ? 128 : 64;
    int off  = (scale == 0) ? 0 : (scale == 1) ? 512 : 768;
    int base = (scale == 0) ? 0 : (scale == 1) ? 8 : 16;   // in block units
    int r0 = (pr - base) * 2;           // rank of first token within scale

    if (t < 64) {                       // wave 0 does the top-k
        float v[4];
#pragma unroll
        for (int j = 0; j < 4; j++) {
            int ii = t + j * 64;
            v[j] = (ii < C) ? final_all[off + b * C + ii] : -INFINITY;
        }
        for (int s = 0; s <= r0 + 1; s++) {
            float bd = v[0]; int bj = 0;
#pragma unroll
            for (int j = 1; j < 4; j++) if (v[j] > bd) { bd = v[j]; bj = j; }
            int bi2 = t + bj * 64;
            float m = wred_max_f32(bd);          // scores > 0, identity 0 safe
            int cand = (bd == m) ? bi2 : 0x7fffffff;
            int wi = wred_min_i32(cand);         // first-index tie-break = lax.top_k
            if (t == (wi & 63)) {
#pragma unroll
                for (int j = 0; j < 4; j++) if (j == (wi >> 6)) v[j] = -INFINITY;
            }
            if (t == 0) {
                if (s == r0)     tokp[0] = idx_all[off + b * C + wi];
                if (s == r0 + 1) tokp[1] = idx_all[off + b * C + wi];
            }
        }
    }
    __syncthreads();

    for (int r = 0; r < 2; r++) {
        int p = tokp[r];
        const float* src = feat + ((size_t)b * N_PTS + p) * D_FEAT;
        for (int c = t; c < 768; c += 256) xt[r * 772 + c] = src[c];
    }
    __syncthreads();

    for (int u = t; u < 768; u += 256) {
        int j = u >> 1, r = u & 1;
        float4 a = make_float4(0, 0, 0, 0);
        for (int k = 0; k < 768; k += 4) {
            float4 wv = *(const float4*)&pW1[(size_t)j * 768 + k];
            float4 x = *(const float4*)&xt[r * 772 + k];
            a.x = fmaf(wv.x, x.x, a.x); a.y = fmaf(wv.y, x.y, a.y);
            a.z = fmaf(wv.z, x.z, a.z); a.w = fmaf(wv.w, x.w, a.w);
        }
        float v = (a.x + a.y) + (a.z + a.w) + pb1[j];
        h1s[r * 388 + j] = fmaxf(v, 0.f);
    }
    __syncthreads();

    for (int u = t; u < 1536; u += 256) {
        int o = u >> 1, r = u & 1;
        float4 a = make_float4(0, 0, 0, 0);
        for (int k = 0; k < 384; k += 4) {
            float4 wv = *(const float4*)&pW2[(size_t)o * 384 + k];
            float4 h = *(const float4*)&h1s[r * 388 + k];
            a.x = fmaf(wv.x, h.x, a.x); a.y = fmaf(wv.y, h.y, a.y);
            a.z = fmaf(wv.z, h.z, a.z); a.w = fmaf(wv.w, h.w, a.w);
        }
        xt[r * 772 + o] = (a.x + a.y) + (a.z + a.w) + pb2[o];
    }
    __syncthreads();

    for (int r = 0; r < 2; r++) {
        float s1 = 0.f, s2 = 0.f;
        for (int o = t; o < 768; o += 256) { float v = xt[r * 772 + o]; s1 += v; s2 += v * v; }
#pragma unroll
        for (int off2 = 32; off2 >= 1; off2 >>= 1) {
            s1 += __shfl_down(s1, off2, 64);
            s2 += __shfl_down(s2, off2, 64);
        }
        int lane = t & 63, wid = t >> 6;
        if (lane == 0) { red[wid * 2] = s1; red[wid * 2 + 1] = s2; }
        __syncthreads();
        float S1 = red[0] + red[2] + red[4] + red[6];
        float S2 = red[1] + red[3] + red[5] + red[7];
        float mu = S1 / 768.0f;
        float var = S2 / 768.0f - mu * mu;
        float inv = rsqrtf(var + 1e-5f);
        float* dst = out + ((size_t)b * 40 + pr * 2 + r) * 768;
        for (int o = t; o < 768; o += 256) {
            float v = xt[r * 772 + o];
            dst[o] = (v - mu) * inv * lng[o] + lnb[o];
        }
        __syncthreads();
    }
}

extern "C" void kernel_launch(void* const* d_in, const int* in_sizes, int n_in,
                              void* d_out, int out_size, void* d_ws, size_t ws_size,
                              hipStream_t stream) {
    const float* feat   = (const float*)d_in[0];
    const float* coords = (const float*)d_in[1];
    const float* gW1 = (const float*)d_in[2],  *gb1 = (const float*)d_in[3];
    const float* gW2 = (const float*)d_in[4],  *gb2 = (const float*)d_in[5];
    const float* cW1 = (const float*)d_in[6],  *cb1 = (const float*)d_in[7];
    const float* cW2 = (const float*)d_in[8],  *cb2 = (const float*)d_in[9];
    const float* dW1 = (const float*)d_in[10], *db1 = (const float*)d_in[11];
    const float* dW2 = (const float*)d_in[12], *db2 = (const float*)d_in[13];
    const float* pW1 = (const float*)d_in[14], *pb1 = (const float*)d_in[15];
    const float* pW2 = (const float*)d_in[16], *pb2 = (const float*)d_in[17];
    const float* lng = (const float*)d_in[18], *lnb = (const float*)d_in[19];
    float* out = (float*)d_out;

    int*   idx_all    = (int*)d_ws;               // 896 ints
    float* safety_all = (float*)d_ws + 896;       // 768 floats used
    float* final_all  = (float*)d_ws + 1792;      // 896 floats

    fps_kernel<<<2, 512, 0, stream>>>(coords, idx_all, safety_all);
    score_kernel<<<112, 256, 0, stream>>>(feat, coords, gW1, gb1, gW2, gb2, cW1, cb1, cW2, cb2,
                                          dW1, db1, dW2, db2, idx_all, safety_all, final_all);
    final_kernel<<<40, 256, 0, stream>>>(feat, idx_all, final_all, pW1, pb1, pW2, pb2, lng, lnb, out);
}